// Round 15
// baseline (595.086 us; speedup 1.0000x reference)
//
#include <hip/hip_runtime.h>
#include <hip/hip_bf16.h>
#include <math.h>

#define NN 10000
#define EE 160000
#define DD 300
#define LL 5
#define GG 64
#define FDIM 512
#define HDIM 256

// padded GEMM dims
#define MP 10112          // 316 * 32
#define KP1 320           // K of GEMM1 (=DD padded), NKS1 = 10
#define NP1 640           // N of GEMM1 (=2D padded)
#define KP2 640           // K of GEMM2, NKS2 = 20
#define NP2 320           // N of GEMM2
#define NKS1 10
#define NKS2 20
#define PROWS 25          // rows per k_pool block
#define PD 384            // hb16 row stride (u16): 768B = 3*256B -> aligned wave loads
#define B1PLANE 204800    // (NP1/16)*NKS1*512 u16 per layer
#define B2PLANE 204800    // (NP2/16)*NKS2*512 u16 per layer
#define NWG 1580          // 5 x-panels * 316 y-panels of 32 rows (both GEMMs)

typedef short bf16x8 __attribute__((ext_vector_type(8)));
typedef float f32x4 __attribute__((ext_vector_type(4)));

// round-to-nearest-even f32 -> bf16 (hi) and hi+lo split
__device__ inline unsigned short bf16hi(float v) {
    unsigned u = __builtin_bit_cast(unsigned, v);
    unsigned r = u + 0x7FFFu + ((u >> 16) & 1u);
    return (unsigned short)(r >> 16);
}
__device__ inline void splitbf(float v, unsigned short& hi, unsigned short& lo) {
    hi = bf16hi(v);
    float hf = __builtin_bit_cast(float, (unsigned)hi << 16);
    lo = bf16hi(v - hf);
}

// fragment-packed element address. For A: row=m, k=k. For B: row=n, k=k.
// frag: lane = (row&15) + 16*((k>>3)&3), elem = k&7, tile = (row>>4)*nks + (k>>5)
__device__ inline size_t packAddr(int row, int k, int nks) {
    return ((size_t)((row >> 4) * nks + (k >> 5)) << 9)
         + (size_t)((((row & 15) + (((k >> 3) & 3) << 4)) << 3) + (k & 7));
}

// ---------------- node embedding -> bf16 plane (PD-padded rows) ----------------
__global__ void k_node_emb(const int* __restrict__ x, const float* __restrict__ e1,
                           const float* __restrict__ e2, unsigned short* __restrict__ hb) {
    int idx = blockIdx.x * blockDim.x + threadIdx.x;
    if (idx >= NN * DD) return;
    int r = idx / DD, c = idx - r * DD;
    int i0 = x[r * 2 + 0], i1 = x[r * 2 + 1];
    hb[(size_t)r * PD + c] = bf16hi(e1[i0 * DD + c] + e2[i1 * DD + c]);
}

// ---------------- CSR build over dst ----------------
__global__ void k_count(const int* __restrict__ edge_index, unsigned* __restrict__ deg) {
    int e = blockIdx.x * blockDim.x + threadIdx.x;
    if (e >= EE + NN) return;
    int dst = (e < EE) ? edge_index[EE + e] : (e - EE);
    atomicAdd(&deg[dst], 1u);
}

__global__ void k_scan(const unsigned* __restrict__ deg, unsigned* __restrict__ row_ptr) {
    __shared__ unsigned sm[256];
    int t = threadIdx.x;
    unsigned loc[40];
    unsigned run = 0;
    int base = t * 40;
#pragma unroll
    for (int i = 0; i < 40; i++) {
        int idx = base + i;
        unsigned d = (idx < NN) ? deg[idx] : 0u;
        loc[i] = run; run += d;
    }
    sm[t] = run;
    __syncthreads();
    for (int off = 1; off < 256; off <<= 1) {
        unsigned v = (t >= off) ? sm[t - off] : 0u;
        __syncthreads();
        sm[t] += v;
        __syncthreads();
    }
    unsigned pre = (t > 0) ? sm[t - 1] : 0u;
#pragma unroll
    for (int i = 0; i < 40; i++) {
        int idx = base + i;
        if (idx < NN) row_ptr[idx] = pre + loc[i];
    }
    if (t == 255) row_ptr[NN] = sm[255];
}

__global__ void k_fill(const int* __restrict__ edge_index, const int* __restrict__ edge_attr,
                       const unsigned* __restrict__ row_ptr, unsigned* __restrict__ cursor,
                       unsigned* __restrict__ eidx) {
    int e = blockIdx.x * blockDim.x + threadIdx.x;
    if (e >= EE + NN) return;
    int src, dst, code;
    if (e < EE) {
        src = edge_index[e];
        dst = edge_index[EE + e];
        const int* ea = edge_attr + e * 10;
        int a0 = ea[0] & 1, a1 = ea[1] & 1, bits = 0;
#pragma unroll
        for (int k = 0; k < 8; k++) bits |= (ea[2 + k] & 1) << k;
        code = a0 | (a1 << 1) | (bits << 2);
    } else {
        src = e - EE; dst = e - EE; code = 1024;
    }
    unsigned pos = atomicAdd(&cursor[dst], 1u);
    eidx[row_ptr[dst] + pos] = (unsigned)src | ((unsigned)code << 16);
}

// ---------------- graph bounds (batch sorted -> unique writers, no atomics) ----------------
__global__ void k_bounds2(const int* __restrict__ batch, int* __restrict__ gs,
                          int* __restrict__ ge) {
    int i = blockIdx.x * blockDim.x + threadIdx.x;
    if (i >= NN) return;
    int g = batch[i];
    if (i == 0 || batch[i - 1] != g) gs[g] = i;
    if (i == NN - 1 || batch[i + 1] != g) ge[g] = i + 1;
}

// ---------------- aggregation: one wave/node, bf16 h reads, unroll-4 ILP ----------------
// channels per lane: c = (q>>1)*128 + 2*lane + (q&1), q=0..5 (q>=4 only lanes<22)
template<int MODE>
__global__ __launch_bounds__(256) void k_gather(
    const unsigned short* __restrict__ hb,
    const unsigned* __restrict__ row_ptr, const unsigned* __restrict__ eidx,
    const float* __restrict__ sums,
    const float* __restrict__ bng, const float* __restrict__ bnb, int lprev,
    const float* __restrict__ ee1, const float* __restrict__ ee2,
    const float* __restrict__ ee3w, const float* __restrict__ ee3b, int l,
    unsigned short* __restrict__ A1hi, unsigned short* __restrict__ A1lo) {
    int wave = threadIdx.x >> 6, lane = threadIdx.x & 63;
    int v = blockIdx.x * 4 + wave;
    if (v >= NN) return;
    const int c2l = 2 * lane;
    const bool has2 = (lane < (DD - 256) / 2);   // lanes 0..21
    float sc[6], sh[6];
    if (MODE == 1) {
#pragma unroll
        for (int q = 0; q < 6; q++) {
            int c = (q >> 1) * 128 + c2l + (q & 1);
            if (q < 4 || has2) {
                float mu = sums[c] * (1.0f / NN);
                float var = sums[304 + c] * (1.0f / NN) - mu * mu;
                float inv = rsqrtf(var + 1e-5f);
                sc[q] = bng[lprev * DD + c] * inv;
                sh[q] = bnb[lprev * DD + c] - mu * sc[q];
            } else { sc[q] = 0.f; sh[q] = 0.f; }
        }
    }
    float a[6] = {0.f, 0.f, 0.f, 0.f, 0.f, 0.f};
    unsigned s = row_ptr[v], e = row_ptr[v + 1];
    unsigned n01 = 0, sb0 = 0, sb1 = 0;
    auto edge = [&](unsigned p) {
        int src = (int)(p & 0xFFFFu);
        unsigned code = p >> 16;
        n01 += (code * 0x8001u) & 0x10001u;
        sb0 += (((code >> 2) & 0xFu) * 0x204081u) & 0x1010101u;
        sb1 += (((code >> 6) & 0xFu) * 0x204081u) & 0x1010101u;
        const unsigned short* hr = hb + (size_t)src * PD;
        unsigned w0 = *(const unsigned*)(hr + c2l);
        unsigned w1 = *(const unsigned*)(hr + 128 + c2l);
        unsigned w2 = has2 ? *(const unsigned*)(hr + 256 + c2l) : 0u;
        float x0 = __builtin_bit_cast(float, w0 << 16);
        float x1 = __builtin_bit_cast(float, w0 & 0xFFFF0000u);
        float x2 = __builtin_bit_cast(float, w1 << 16);
        float x3 = __builtin_bit_cast(float, w1 & 0xFFFF0000u);
        float x4 = __builtin_bit_cast(float, w2 << 16);
        float x5 = __builtin_bit_cast(float, w2 & 0xFFFF0000u);
        if (MODE == 1) {
            x0 = fmaxf(fmaf(x0, sc[0], sh[0]), 0.f);
            x1 = fmaxf(fmaf(x1, sc[1], sh[1]), 0.f);
            x2 = fmaxf(fmaf(x2, sc[2], sh[2]), 0.f);
            x3 = fmaxf(fmaf(x3, sc[3], sh[3]), 0.f);
            x4 = fmaxf(fmaf(x4, sc[4], sh[4]), 0.f);
            x5 = fmaxf(fmaf(x5, sc[5], sh[5]), 0.f);
        }
        a[0] += x0; a[1] += x1; a[2] += x2; a[3] += x3; a[4] += x4; a[5] += x5;
    };
    // unroll-4: 4 sequential eidx reads (merge to dwordx4) -> 12 h-row loads in flight
    unsigned i = s;
    for (; i + 3 < e; i += 4) {
        unsigned p0 = eidx[i], p1 = eidx[i + 1], p2 = eidx[i + 2], p3 = eidx[i + 3];
        edge(p0); edge(p1); edge(p2); edge(p3);
    }
    for (; i < e; ++i) edge(eidx[i]);

    float deg = (float)(e - s);
    float na0 = (float)(n01 & 0xFFFFu);
    float na1 = (float)(n01 >> 16);
    float sb[8] = {(float)(sb0 & 255u), (float)((sb0 >> 8) & 255u),
                   (float)((sb0 >> 16) & 255u), (float)(sb0 >> 24),
                   (float)(sb1 & 255u), (float)((sb1 >> 8) & 255u),
                   (float)((sb1 >> 16) & 255u), (float)(sb1 >> 24)};
    const float* E10 = ee1 + (size_t)(l * 6 + 0) * DD;
    const float* E11 = ee1 + (size_t)(l * 6 + 1) * DD;
    const float* E14 = ee1 + (size_t)(l * 6 + 4) * DD;
    const float* E20 = ee2 + (size_t)(l * 4 + 0) * DD;
    const float* E21 = ee2 + (size_t)(l * 4 + 1) * DD;
    const float* B3  = ee3b + (size_t)l * DD;
    unsigned short hi, lo;
    size_t ad;
#pragma unroll
    for (int q = 0; q < 6; q++) {
        if (q < 4 || has2) {
            int c = (q >> 1) * 128 + c2l + (q & 1);
            float t = a[q];
            t += (deg - 1.f - na0) * E10[c] + na0 * E11[c] + E14[c];
            t += (deg - na1) * E20[c] + na1 * E21[c];
            t += deg * B3[c];
#pragma unroll
            for (int k = 0; k < 8; k++)
                t += sb[k] * (ee3w + (size_t)(l * 8 + k) * DD)[c];
            splitbf(t, hi, lo);
            ad = packAddr(v, c, NKS1);
            A1hi[ad] = hi; A1lo[ad] = lo;
        }
    }
    // CRITICAL: zero the k-padding columns [300,320). A1hi aliases d_out, so on
    // graph replays this region holds recycled h_node bytes which can decode to
    // bf16 NaN/Inf; NaN * 0 (zero-padded B) = NaN poisons entire C rows.
    if (lane < KP1 - DD) {
        ad = packAddr(v, DD + lane, NKS1);
        A1hi[ad] = 0; A1lo[ad] = 0;
    }
}

// ---------------- weight pack for ALL layers (zero-fills padding) ----------------
__global__ void k_packAll(const float* __restrict__ mlp_w1, const float* __restrict__ mlp_w2,
                          unsigned short* __restrict__ B1hi, unsigned short* __restrict__ B1lo,
                          unsigned short* __restrict__ B2hi, unsigned short* __restrict__ B2lo) {
    const int PER = KP1 * NP1 + KP2 * NP2;
    int idx = blockIdx.x * blockDim.x + threadIdx.x;
    int l = idx / PER;
    if (l >= LL) return;
    int r = idx - l * PER;
    unsigned short hi, lo;
    if (r < KP1 * NP1) {
        int nn = r / KP1, kk = r - nn * KP1;
        float v = (kk < DD && nn < 2 * DD)
                ? mlp_w1[(size_t)l * DD * 2 * DD + (size_t)kk * (2 * DD) + nn] : 0.f;
        splitbf(v, hi, lo);
        size_t a = (size_t)l * B1PLANE + packAddr(nn, kk, NKS1);
        B1hi[a] = hi; B1lo[a] = lo;
    } else {
        r -= KP1 * NP1;
        int nn = r / KP2, kk = r - nn * KP2;
        float v = (kk < 2 * DD && nn < DD)
                ? mlp_w2[(size_t)l * 2 * DD * DD + (size_t)kk * DD + nn] : 0.f;
        splitbf(v, hi, lo);
        size_t a = (size_t)l * B2PLANE + packAddr(nn, kk, NKS2);
        B2hi[a] = hi; B2lo[a] = lo;
    }
}

// ---------------- MFMA GEMM: 32-row blocks, XCD swizzle, 2-deep register pipeline ----------------
// 4 waves: wm=wave>>1 (1 m-tile each), wn=wave&1 (NF n-frags each). BNT = 32*NF.
// Grid NWG=1580 (~6 blocks/CU) for TLP; fragments of ks+1 loaded before ks's MFMAs.
// EPI 0: relu(acc+bias) -> packed bf16 hi/lo (next GEMM's A)
// EPI 1: acc+bias -> bf16 h plane (PD-padded) (+ optional f32 C) + fused BN stats
template<int NF, int NKS, int EPI>
__global__ __launch_bounds__(256) void k_mgemm(
    const unsigned short* __restrict__ Ahi, const unsigned short* __restrict__ Alo,
    const unsigned short* __restrict__ Bhi, const unsigned short* __restrict__ Blo,
    const float* __restrict__ bias, int realN,
    float* __restrict__ Cf32, int realM,
    unsigned short* __restrict__ Phi, unsigned short* __restrict__ Plo, int nks_out,
    float* __restrict__ sums, unsigned short* __restrict__ Hb16) {
    constexpr int BNT = 32 * NF;
    // bijective XCD swizzle (m204): NWG=1580, q=197, r=4.
    int orig = blockIdx.x;
    int xcd = orig & 7, rem = orig >> 3;
    int wgid = (xcd < 4 ? xcd * 198 : 792 + (xcd - 4) * 197) + rem;
    int by = wgid / 5;          // 316 m-panels of 32 rows
    int bx = wgid - by * 5;     // 5 n-panels of BNT cols
    int tid = threadIdx.x;
    int lane = tid & 63, wave = tid >> 6;
    int wm = wave >> 1, wn = wave & 1;
    int mt0 = by * 2 + wm;      // single 16-row tile per wave
    int nt0 = bx * (2 * NF) + wn * NF;
    const int laneo = lane * 8;

    struct Frag { bf16x8 ah, al, bh[NF], bl[NF]; };
    auto loadF = [&](int ks, Frag& f) {
        size_t aoff = ((size_t)(mt0 * NKS + ks) << 9) + laneo;
        f.ah = *(const bf16x8*)(Ahi + aoff);
        f.al = *(const bf16x8*)(Alo + aoff);
#pragma unroll
        for (int j = 0; j < NF; j++) {
            size_t off = ((size_t)((nt0 + j) * NKS + ks) << 9) + laneo;
            f.bh[j] = *(const bf16x8*)(Bhi + off);
            f.bl[j] = *(const bf16x8*)(Blo + off);
        }
    };

    f32x4 acc[NF];
#pragma unroll
    for (int j = 0; j < NF; j++) acc[j] = (f32x4){0.f, 0.f, 0.f, 0.f};

    Frag cur, nxt;
    loadF(0, cur);
#pragma unroll
    for (int ks = 0; ks < NKS; ++ks) {
        if (ks + 1 < NKS) loadF(ks + 1, nxt);   // issue next-stage loads first
#pragma unroll
        for (int j = 0; j < NF; j++) {
            acc[j] = __builtin_amdgcn_mfma_f32_16x16x32_bf16(cur.ah, cur.bh[j], acc[j], 0, 0, 0);
            acc[j] = __builtin_amdgcn_mfma_f32_16x16x32_bf16(cur.ah, cur.bl[j], acc[j], 0, 0, 0);
            acc[j] = __builtin_amdgcn_mfma_f32_16x16x32_bf16(cur.al, cur.bh[j], acc[j], 0, 0, 0);
        }
        if (ks + 1 < NKS) cur = nxt;
    }

    int crow = (lane >> 4) * 4;
    int ccol = lane & 15;
    float s_loc[NF], q_loc[NF];
#pragma unroll
    for (int j = 0; j < NF; j++) { s_loc[j] = 0.f; q_loc[j] = 0.f; }
    int rowb = mt0 * 16 + crow;
#pragma unroll
    for (int j = 0; j < NF; j++) {
        int col = (nt0 + j) * 16 + ccol;
        float bv = (col < realN) ? bias[col] : 0.f;
#pragma unroll
        for (int r = 0; r < 4; r++) {
            int row = rowb + r;
            float v = acc[j][r] + bv;
            if (EPI == 0) {
                v = fmaxf(v, 0.f);
                unsigned short hi, lo;
                splitbf(v, hi, lo);
                size_t a = packAddr(row, col, nks_out);
                Phi[a] = hi; Plo[a] = lo;
            } else {
                if (row < realM) {
                    s_loc[j] += v;
                    q_loc[j] += v * v;
                    if (col < realN) {
                        Hb16[(size_t)row * PD + col] = bf16hi(v);
                        if (Cf32) Cf32[(size_t)row * realN + col] = v;
                    }
                }
            }
        }
    }
    if constexpr (EPI == 1) {
        __shared__ float sms[BNT][8];
        __shared__ float smq[BNT][8];
        int slot = wm * 4 + (lane >> 4);
#pragma unroll
        for (int j = 0; j < NF; j++) {
            int cl = (wn * NF + j) * 16 + ccol;
            sms[cl][slot] = s_loc[j];
            smq[cl][slot] = q_loc[j];
        }
        __syncthreads();
        if (tid < BNT) {
            float ss = 0.f, qq = 0.f;
#pragma unroll
            for (int k = 0; k < 8; k++) { ss += sms[tid][k]; qq += smq[tid][k]; }
            int col = bx * BNT + tid;
            if (col < realN) {
                atomicAdd(&sums[col], ss);
                atomicAdd(&sums[304 + col], qq);
            }
        }
    }
}

// final-layer BN apply (writes h_node to d_out, no relu)
__global__ void k_bnapply(const float* __restrict__ hin, const float* __restrict__ sums,
                          const float* __restrict__ g, const float* __restrict__ b,
                          float* __restrict__ hout, int l, int relu) {
    int idx = blockIdx.x * blockDim.x + threadIdx.x;
    if (idx >= NN * DD) return;
    int c = idx % DD;
    const float invn = 1.0f / NN;
    float mu = sums[c] * invn;
    float var = sums[304 + c] * invn - mu * mu;
    float inv = rsqrtf(var + 1e-5f);
    float v = (hin[idx] - mu) * inv * g[l * DD + c] + b[l * DD + c];
    if (relu) v = fmaxf(v, 0.f);
    hout[idx] = v;
}

// ---------------- parallel pooling: run-length partial sums + atomics ----------------
__global__ __launch_bounds__(320) void k_pool(const float* __restrict__ h,
                                              const int* __restrict__ batch,
                                              float* __restrict__ pooled) {
    int c = threadIdx.x;
    if (c >= DD) return;
    int r0 = blockIdx.x * PROWS;
    int r1 = min(r0 + PROWS, NN);
    if (r0 >= NN) return;
    int gc = batch[r0];
    float acc = 0.f;
    for (int r = r0; r < r1; ++r) {
        int g = batch[r];
        if (g != gc) {
            atomicAdd(&pooled[gc * DD + c], acc);
            acc = 0.f; gc = g;
        }
        acc += h[(size_t)r * DD + c];
    }
    atomicAdd(&pooled[gc * DD + c], acc);
}

// ---------------- head GEMM (split-K) ----------------
template<int KD, int NW, int ACT>
__global__ __launch_bounds__(256) void k_hgemm(
    const float* __restrict__ A, const float* __restrict__ W,
    const float* __restrict__ bias, float* __restrict__ outp,
    const int* __restrict__ gs, const int* __restrict__ ge) {
    __shared__ float smA[KD];
    __shared__ float smR[8][32];
    int g = blockIdx.y;
    int t = threadIdx.x;
    float mul = 1.f;
    if (gs) {
        int cnt = ge[g] - gs[g];
        mul = 1.f / (float)((cnt > 0) ? cnt : 1);
    }
    for (int k = t; k < KD; k += 256) smA[k] = A[(size_t)g * KD + k] * mul;
    __syncthreads();
    int c = blockIdx.x * 32 + (t & 31);
    int s = t >> 5;
    float acc = 0.f;
#pragma unroll 4
    for (int k = s; k < KD; k += 8)
        acc = fmaf(smA[k], W[(size_t)k * NW + c], acc);
    smR[s][t & 31] = acc;
    __syncthreads();
    if (t < 32) {
        float r = bias[c];
#pragma unroll
        for (int i = 0; i < 8; i++) r += smR[i][t];
        if (ACT) r = fmaxf(r, 0.f) + log1pf(expf(-fabsf(r)));
        outp[(size_t)g * NW + c] = r;
    }
}

__global__ __launch_bounds__(256) void k_hfinal(const float* __restrict__ z,
                                                const float* __restrict__ w,
                                                const float* __restrict__ b,
                                                float* __restrict__ pred) {
    __shared__ float smR[4];
    int g = blockIdx.x, t = threadIdx.x;
    float rv = z[(size_t)g * HDIM + t] * w[t];
#pragma unroll
    for (int off = 32; off > 0; off >>= 1) rv += __shfl_down(rv, off, 64);
    if ((t & 63) == 0) smR[t >> 6] = rv;
    __syncthreads();
    if (t == 0) pred[g] = smR[0] + smR[1] + smR[2] + smR[3] + b[0];
}

extern "C" void kernel_launch(void* const* d_in, const int* in_sizes, int n_in,
                              void* d_out, int out_size, void* d_ws, size_t ws_size,
                              hipStream_t stream) {
    const int* x          = (const int*)d_in[0];
    const int* edge_index = (const int*)d_in[1];
    const int* edge_attr  = (const int*)d_in[2];
    const int* batch      = (const int*)d_in[3];
    const float* x_emb1   = (const float*)d_in[4];
    const float* x_emb2   = (const float*)d_in[5];
    const float* mlp_w1   = (const float*)d_in[6];
    const float* mlp_b1   = (const float*)d_in[7];
    const float* mlp_w2   = (const float*)d_in[8];
    const float* mlp_b2   = (const float*)d_in[9];
    const float* ee1      = (const float*)d_in[10];
    const float* ee2      = (const float*)d_in[11];
    const float* ee3w     = (const float*)d_in[12];
    const float* ee3b     = (const float*)d_in[13];
    const float* bng      = (const float*)d_in[14];
    const float* bnb      = (const float*)d_in[15];
    const float* feat_w   = (const float*)d_in[16];
    const float* feat_b   = (const float*)d_in[17];
    const float* ph_w1    = (const float*)d_in[18];
    const float* ph_b1    = (const float*)d_in[19];
    const float* ph_w2    = (const float*)d_in[20];
    const float* ph_b2    = (const float*)d_in[21];
    const float* ph_w3    = (const float*)d_in[22];
    const float* ph_b3    = (const float*)d_in[23];
    float* out = (float*)d_out;

    // workspace layout (f32 elements)
    float* fws = (float*)d_ws;
    size_t o = 0;
    float* hbuf  = fws + o; o += (size_t)NN * DD;                    // f32 h_pre (final layer only)
    unsigned short* hb16 = (unsigned short*)(fws + o); o += (size_t)NN * PD / 2 + 8;  // bf16 h plane (PD stride)
    float* hf    = fws + o; o += (size_t)GG * FDIM;
    float* z1    = fws + o; o += (size_t)GG * HDIM;
    float* z2    = fws + o; o += (size_t)GG * HDIM;
    unsigned short* A1lo = (unsigned short*)(fws + o); o += (size_t)(MP/16) * NKS1 * 512 / 2;
    unsigned short* A2hi = (unsigned short*)(fws + o); o += (size_t)(MP/16) * NKS2 * 512 / 2;
    unsigned short* A2lo = (unsigned short*)(fws + o); o += (size_t)(MP/16) * NKS2 * 512 / 2;
    unsigned short* B1hi = (unsigned short*)(fws + o); o += (size_t)LL * B1PLANE / 2;
    unsigned short* B1lo = (unsigned short*)(fws + o); o += (size_t)LL * B1PLANE / 2;
    unsigned short* B2hi = (unsigned short*)(fws + o); o += (size_t)LL * B2PLANE / 2;
    unsigned short* B2lo = (unsigned short*)(fws + o); o += (size_t)LL * B2PLANE / 2;
    unsigned* rowptr = (unsigned*)(fws + o); o += NN + 8;
    unsigned* eidx   = (unsigned*)(fws + o); o += EE + NN;
    // ---- zeroed region (single memset) ----
    float* zbase = fws + o;
    unsigned* deg    = (unsigned*)(fws + o); o += NN;
    unsigned* cursor = (unsigned*)(fws + o); o += NN;
    float* sumsL  = fws + o; o += 5 * 640;       // per-layer BN stats
    float* pooled = fws + o; o += (size_t)GG * DD;
    int* gs = (int*)(fws + o); o += GG;
    int* ge = (int*)(fws + o); o += GG;
    size_t zbytes = (size_t)((char*)(fws + o) - (char*)zbase);
    (void)ws_size; (void)in_sizes; (void)n_in; (void)out_size;

    // A1hi aliases d_out (scratch until final bnapply overwrites it)
    unsigned short* A1hi = (unsigned short*)out;

    const int TPB = 256;
    int gridE = (EE + NN + TPB - 1) / TPB;
    int gridND = (NN * DD + TPB - 1) / TPB;

    hipMemsetAsync(zbase, 0, zbytes, stream);
    k_node_emb<<<gridND, TPB, 0, stream>>>(x, x_emb1, x_emb2, hb16);
    k_count<<<gridE, TPB, 0, stream>>>(edge_index, deg);
    k_scan<<<1, 256, 0, stream>>>(deg, rowptr);
    k_fill<<<gridE, TPB, 0, stream>>>(edge_index, edge_attr, rowptr, cursor, eidx);
    k_bounds2<<<(NN + TPB - 1) / TPB, TPB, 0, stream>>>(batch, gs, ge);
    k_packAll<<<(LL * (KP1 * NP1 + KP2 * NP2) + TPB - 1) / TPB, TPB, 0, stream>>>(
        mlp_w1, mlp_w2, B1hi, B1lo, B2hi, B2lo);

    for (int l = 0; l < LL; ++l) {
        if (l == 0)
            k_gather<0><<<NN / 4, TPB, 0, stream>>>(hb16, rowptr, eidx,
                nullptr, nullptr, nullptr, 0, ee1, ee2, ee3w, ee3b, l, A1hi, A1lo);
        else
            k_gather<1><<<NN / 4, TPB, 0, stream>>>(hb16, rowptr, eidx,
                sumsL + (size_t)(l - 1) * 640, bng, bnb, l - 1,
                ee1, ee2, ee3w, ee3b, l, A1hi, A1lo);
        // GEMM1: [MP,320] x [320,640] -> relu -> packed A2   (NF=4 -> BNT=128)
        k_mgemm<4, NKS1, 0><<<NWG, 256, 0, stream>>>(
            A1hi, A1lo, B1hi + (size_t)l * B1PLANE, B1lo + (size_t)l * B1PLANE,
            mlp_b1 + (size_t)l * 2 * DD, 2 * DD,
            nullptr, 0, A2hi, A2lo, NKS2, nullptr, nullptr);
        // GEMM2: [MP,640] x [640,320] -> bf16 h plane (+ f32 final layer) + BN stats (NF=2 -> BNT=64)
        k_mgemm<2, NKS2, 1><<<NWG, 256, 0, stream>>>(
            A2hi, A2lo, B2hi + (size_t)l * B2PLANE, B2lo + (size_t)l * B2PLANE,
            mlp_b2 + (size_t)l * DD, DD,
            (l == LL - 1) ? hbuf : nullptr, NN, nullptr, nullptr, 0,
            sumsL + (size_t)l * 640, hb16);
    }
    // final layer BN -> h_node output (no relu)
    k_bnapply<<<gridND, TPB, 0, stream>>>(hbuf, sumsL + 4 * 640, bng, bnb, out, LL - 1, 0);

    k_pool<<<(NN + PROWS - 1) / PROWS, 320, 0, stream>>>(out, batch, pooled);
    k_hgemm<DD, FDIM, 0><<<dim3(FDIM / 32, GG), 256, 0, stream>>>(pooled, feat_w, feat_b, hf, gs, ge);
    k_hgemm<FDIM, HDIM, 1><<<dim3(HDIM / 32, GG), 256, 0, stream>>>(hf, ph_w1, ph_b1, z1, nullptr, nullptr);
    k_hgemm<HDIM, HDIM, 1><<<dim3(HDIM / 32, GG), 256, 0, stream>>>(z1, ph_w2, ph_b2, z2, nullptr, nullptr);
    k_hfinal<<<GG, 256, 0, stream>>>(z2, ph_w3, ph_b3, out + (size_t)NN * DD);
}

// Round 16
// 550.758 us; speedup vs baseline: 1.0805x; 1.0805x over previous
//
#include <hip/hip_runtime.h>
#include <hip/hip_bf16.h>
#include <math.h>

#define NN 10000
#define EE 160000
#define DD 300
#define LL 5
#define GG 64
#define FDIM 512
#define HDIM 256

// padded GEMM dims
#define MP 10112          // 158 * 64
#define KP1 320           // K of GEMM1 (=DD padded), NKS1 = 10
#define NP1 640           // N of GEMM1 (=2D padded)
#define KP2 640           // K of GEMM2, NKS2 = 20
#define NP2 320           // N of GEMM2
#define NKS1 10
#define NKS2 20
#define PROWS 25          // rows per k_pool block
#define PD 384            // hb16 row stride (u16): 768B = 3*256B -> aligned wave loads
#define B1PLANE 204800    // (NP1/16)*NKS1*512 u16 per layer
#define B2PLANE 204800    // (NP2/16)*NKS2*512 u16 per layer
#define NWG 790           // 5 x-panels * 158 y-panels of 64 rows (both GEMMs)

typedef short bf16x8 __attribute__((ext_vector_type(8)));
typedef float f32x4 __attribute__((ext_vector_type(4)));

// round-to-nearest-even f32 -> bf16 (hi) and hi+lo split
__device__ inline unsigned short bf16hi(float v) {
    unsigned u = __builtin_bit_cast(unsigned, v);
    unsigned r = u + 0x7FFFu + ((u >> 16) & 1u);
    return (unsigned short)(r >> 16);
}
__device__ inline void splitbf(float v, unsigned short& hi, unsigned short& lo) {
    hi = bf16hi(v);
    float hf = __builtin_bit_cast(float, (unsigned)hi << 16);
    lo = bf16hi(v - hf);
}

// fragment-packed element address. For A: row=m, k=k. For B: row=n, k=k.
// frag: lane = (row&15) + 16*((k>>3)&3), elem = k&7, tile = (row>>4)*nks + (k>>5)
__device__ inline size_t packAddr(int row, int k, int nks) {
    return ((size_t)((row >> 4) * nks + (k >> 5)) << 9)
         + (size_t)((((row & 15) + (((k >> 3) & 3) << 4)) << 3) + (k & 7));
}

// ---------------- node embedding -> bf16 plane (PD-padded rows) ----------------
__global__ void k_node_emb(const int* __restrict__ x, const float* __restrict__ e1,
                           const float* __restrict__ e2, unsigned short* __restrict__ hb) {
    int idx = blockIdx.x * blockDim.x + threadIdx.x;
    if (idx >= NN * DD) return;
    int r = idx / DD, c = idx - r * DD;
    int i0 = x[r * 2 + 0], i1 = x[r * 2 + 1];
    hb[(size_t)r * PD + c] = bf16hi(e1[i0 * DD + c] + e2[i1 * DD + c]);
}

// ---------------- CSR build over dst ----------------
__global__ void k_count(const int* __restrict__ edge_index, unsigned* __restrict__ deg) {
    int e = blockIdx.x * blockDim.x + threadIdx.x;
    if (e >= EE + NN) return;
    int dst = (e < EE) ? edge_index[EE + e] : (e - EE);
    atomicAdd(&deg[dst], 1u);
}

__global__ void k_scan(const unsigned* __restrict__ deg, unsigned* __restrict__ row_ptr) {
    __shared__ unsigned sm[256];
    int t = threadIdx.x;
    unsigned loc[40];
    unsigned run = 0;
    int base = t * 40;
#pragma unroll
    for (int i = 0; i < 40; i++) {
        int idx = base + i;
        unsigned d = (idx < NN) ? deg[idx] : 0u;
        loc[i] = run; run += d;
    }
    sm[t] = run;
    __syncthreads();
    for (int off = 1; off < 256; off <<= 1) {
        unsigned v = (t >= off) ? sm[t - off] : 0u;
        __syncthreads();
        sm[t] += v;
        __syncthreads();
    }
    unsigned pre = (t > 0) ? sm[t - 1] : 0u;
#pragma unroll
    for (int i = 0; i < 40; i++) {
        int idx = base + i;
        if (idx < NN) row_ptr[idx] = pre + loc[i];
    }
    if (t == 255) row_ptr[NN] = sm[255];
}

__global__ void k_fill(const int* __restrict__ edge_index, const int* __restrict__ edge_attr,
                       const unsigned* __restrict__ row_ptr, unsigned* __restrict__ cursor,
                       unsigned* __restrict__ eidx) {
    int e = blockIdx.x * blockDim.x + threadIdx.x;
    if (e >= EE + NN) return;
    int src, dst, code;
    if (e < EE) {
        src = edge_index[e];
        dst = edge_index[EE + e];
        const int* ea = edge_attr + e * 10;
        int a0 = ea[0] & 1, a1 = ea[1] & 1, bits = 0;
#pragma unroll
        for (int k = 0; k < 8; k++) bits |= (ea[2 + k] & 1) << k;
        code = a0 | (a1 << 1) | (bits << 2);
    } else {
        src = e - EE; dst = e - EE; code = 1024;
    }
    unsigned pos = atomicAdd(&cursor[dst], 1u);
    eidx[row_ptr[dst] + pos] = (unsigned)src | ((unsigned)code << 16);
}

// ---------------- graph bounds (batch sorted -> unique writers, no atomics) ----------------
__global__ void k_bounds2(const int* __restrict__ batch, int* __restrict__ gs,
                          int* __restrict__ ge) {
    int i = blockIdx.x * blockDim.x + threadIdx.x;
    if (i >= NN) return;
    int g = batch[i];
    if (i == 0 || batch[i - 1] != g) gs[g] = i;
    if (i == NN - 1 || batch[i + 1] != g) ge[g] = i + 1;
}

// ---------------- aggregation: one wave/node, bf16 h reads (PD stride), unroll-4 ILP ----------------
// channels per lane: c = (q>>1)*128 + 2*lane + (q&1), q=0..5 (q>=4 only lanes<22)
template<int MODE>
__global__ __launch_bounds__(256) void k_gather(
    const unsigned short* __restrict__ hb,
    const unsigned* __restrict__ row_ptr, const unsigned* __restrict__ eidx,
    const float* __restrict__ sums,
    const float* __restrict__ bng, const float* __restrict__ bnb, int lprev,
    const float* __restrict__ ee1, const float* __restrict__ ee2,
    const float* __restrict__ ee3w, const float* __restrict__ ee3b, int l,
    unsigned short* __restrict__ A1hi, unsigned short* __restrict__ A1lo) {
    int wave = threadIdx.x >> 6, lane = threadIdx.x & 63;
    int v = blockIdx.x * 4 + wave;
    if (v >= NN) return;
    const int c2l = 2 * lane;
    const bool has2 = (lane < (DD - 256) / 2);   // lanes 0..21
    float sc[6], sh[6];
    if (MODE == 1) {
#pragma unroll
        for (int q = 0; q < 6; q++) {
            int c = (q >> 1) * 128 + c2l + (q & 1);
            if (q < 4 || has2) {
                float mu = sums[c] * (1.0f / NN);
                float var = sums[304 + c] * (1.0f / NN) - mu * mu;
                float inv = rsqrtf(var + 1e-5f);
                sc[q] = bng[lprev * DD + c] * inv;
                sh[q] = bnb[lprev * DD + c] - mu * sc[q];
            } else { sc[q] = 0.f; sh[q] = 0.f; }
        }
    }
    float a[6] = {0.f, 0.f, 0.f, 0.f, 0.f, 0.f};
    unsigned s = row_ptr[v], e = row_ptr[v + 1];
    unsigned n01 = 0, sb0 = 0, sb1 = 0;
    auto edge = [&](unsigned p) {
        int src = (int)(p & 0xFFFFu);
        unsigned code = p >> 16;
        n01 += (code * 0x8001u) & 0x10001u;
        sb0 += (((code >> 2) & 0xFu) * 0x204081u) & 0x1010101u;
        sb1 += (((code >> 6) & 0xFu) * 0x204081u) & 0x1010101u;
        const unsigned short* hr = hb + (size_t)src * PD;
        unsigned w0 = *(const unsigned*)(hr + c2l);
        unsigned w1 = *(const unsigned*)(hr + 128 + c2l);
        unsigned w2 = has2 ? *(const unsigned*)(hr + 256 + c2l) : 0u;
        float x0 = __builtin_bit_cast(float, w0 << 16);
        float x1 = __builtin_bit_cast(float, w0 & 0xFFFF0000u);
        float x2 = __builtin_bit_cast(float, w1 << 16);
        float x3 = __builtin_bit_cast(float, w1 & 0xFFFF0000u);
        float x4 = __builtin_bit_cast(float, w2 << 16);
        float x5 = __builtin_bit_cast(float, w2 & 0xFFFF0000u);
        if (MODE == 1) {
            x0 = fmaxf(fmaf(x0, sc[0], sh[0]), 0.f);
            x1 = fmaxf(fmaf(x1, sc[1], sh[1]), 0.f);
            x2 = fmaxf(fmaf(x2, sc[2], sh[2]), 0.f);
            x3 = fmaxf(fmaf(x3, sc[3], sh[3]), 0.f);
            x4 = fmaxf(fmaf(x4, sc[4], sh[4]), 0.f);
            x5 = fmaxf(fmaf(x5, sc[5], sh[5]), 0.f);
        }
        a[0] += x0; a[1] += x1; a[2] += x2; a[3] += x3; a[4] += x4; a[5] += x5;
    };
    // unroll-4: 4 sequential eidx reads (merge to dwordx4) -> 12 h-row loads in flight
    unsigned i = s;
    for (; i + 3 < e; i += 4) {
        unsigned p0 = eidx[i], p1 = eidx[i + 1], p2 = eidx[i + 2], p3 = eidx[i + 3];
        edge(p0); edge(p1); edge(p2); edge(p3);
    }
    for (; i < e; ++i) edge(eidx[i]);

    float deg = (float)(e - s);
    float na0 = (float)(n01 & 0xFFFFu);
    float na1 = (float)(n01 >> 16);
    float sb[8] = {(float)(sb0 & 255u), (float)((sb0 >> 8) & 255u),
                   (float)((sb0 >> 16) & 255u), (float)(sb0 >> 24),
                   (float)(sb1 & 255u), (float)((sb1 >> 8) & 255u),
                   (float)((sb1 >> 16) & 255u), (float)(sb1 >> 24)};
    const float* E10 = ee1 + (size_t)(l * 6 + 0) * DD;
    const float* E11 = ee1 + (size_t)(l * 6 + 1) * DD;
    const float* E14 = ee1 + (size_t)(l * 6 + 4) * DD;
    const float* E20 = ee2 + (size_t)(l * 4 + 0) * DD;
    const float* E21 = ee2 + (size_t)(l * 4 + 1) * DD;
    const float* B3  = ee3b + (size_t)l * DD;
    unsigned short hi, lo;
    size_t ad;
#pragma unroll
    for (int q = 0; q < 6; q++) {
        if (q < 4 || has2) {
            int c = (q >> 1) * 128 + c2l + (q & 1);
            float t = a[q];
            t += (deg - 1.f - na0) * E10[c] + na0 * E11[c] + E14[c];
            t += (deg - na1) * E20[c] + na1 * E21[c];
            t += deg * B3[c];
#pragma unroll
            for (int k = 0; k < 8; k++)
                t += sb[k] * (ee3w + (size_t)(l * 8 + k) * DD)[c];
            splitbf(t, hi, lo);
            ad = packAddr(v, c, NKS1);
            A1hi[ad] = hi; A1lo[ad] = lo;
        }
    }
    // CRITICAL: zero the k-padding columns [300,320). A1hi aliases d_out, so on
    // graph replays this region holds recycled h_node bytes which can decode to
    // bf16 NaN/Inf; NaN * 0 (zero-padded B) = NaN poisons entire C rows.
    if (lane < KP1 - DD) {
        ad = packAddr(v, DD + lane, NKS1);
        A1hi[ad] = 0; A1lo[ad] = 0;
    }
}

// ---------------- weight pack for ALL layers (zero-fills padding) ----------------
__global__ void k_packAll(const float* __restrict__ mlp_w1, const float* __restrict__ mlp_w2,
                          unsigned short* __restrict__ B1hi, unsigned short* __restrict__ B1lo,
                          unsigned short* __restrict__ B2hi, unsigned short* __restrict__ B2lo) {
    const int PER = KP1 * NP1 + KP2 * NP2;
    int idx = blockIdx.x * blockDim.x + threadIdx.x;
    int l = idx / PER;
    if (l >= LL) return;
    int r = idx - l * PER;
    unsigned short hi, lo;
    if (r < KP1 * NP1) {
        int nn = r / KP1, kk = r - nn * KP1;
        float v = (kk < DD && nn < 2 * DD)
                ? mlp_w1[(size_t)l * DD * 2 * DD + (size_t)kk * (2 * DD) + nn] : 0.f;
        splitbf(v, hi, lo);
        size_t a = (size_t)l * B1PLANE + packAddr(nn, kk, NKS1);
        B1hi[a] = hi; B1lo[a] = lo;
    } else {
        r -= KP1 * NP1;
        int nn = r / KP2, kk = r - nn * KP2;
        float v = (kk < 2 * DD && nn < DD)
                ? mlp_w2[(size_t)l * 2 * DD * DD + (size_t)kk * DD + nn] : 0.f;
        splitbf(v, hi, lo);
        size_t a = (size_t)l * B2PLANE + packAddr(nn, kk, NKS2);
        B2hi[a] = hi; B2lo[a] = lo;
    }
}

// ---------------- MFMA GEMM: 64-row blocks, XCD swizzle, 2-deep register pipeline ----------------
// 4 waves: wm=wave>>1 (2 m-tiles each), wn=wave&1 (NF n-frags each). BNT = 32*NF.
// K-loop fully unrolled; fragments for ks+1 are loaded into a second register set
// BEFORE the MFMAs of ks (loads independent of MFMAs -> L2 latency hides under MFMA).
// EPI 0: relu(acc+bias) -> packed bf16 hi/lo (next GEMM's A)
// EPI 1: acc+bias -> bf16 h plane (PD stride) (+ optional f32 C) + fused BN stats
template<int NF, int NKS, int EPI>
__global__ __launch_bounds__(256) void k_mgemm(
    const unsigned short* __restrict__ Ahi, const unsigned short* __restrict__ Alo,
    const unsigned short* __restrict__ Bhi, const unsigned short* __restrict__ Blo,
    const float* __restrict__ bias, int realN,
    float* __restrict__ Cf32, int realM,
    unsigned short* __restrict__ Phi, unsigned short* __restrict__ Plo, int nks_out,
    float* __restrict__ sums, unsigned short* __restrict__ Hb16) {
    constexpr int BNT = 32 * NF;
    // bijective XCD swizzle (m204): NWG=790, q=98, r=6; same-XCD blocks get
    // consecutive wgid -> complete 5-x-panel groups -> A-panel L2 reuse per XCD.
    int orig = blockIdx.x;
    int xcd = orig & 7, rem = orig >> 3;
    int wgid = (xcd < 6 ? xcd * 99 : 594 + (xcd - 6) * 98) + rem;
    int by = wgid / 5;          // 158 m-panels of 64 rows
    int bx = wgid - by * 5;     // 5 n-panels of BNT cols
    int tid = threadIdx.x;
    int lane = tid & 63, wave = tid >> 6;
    int wm = wave >> 1, wn = wave & 1;
    int mt0 = by * 4 + wm * 2;
    int nt0 = bx * (2 * NF) + wn * NF;
    const int laneo = lane * 8;

    struct Frag { bf16x8 ah[2], al[2], bh[NF], bl[NF]; };
    auto loadF = [&](int ks, Frag& f) {
#pragma unroll
        for (int i = 0; i < 2; i++) {
            size_t off = ((size_t)((mt0 + i) * NKS + ks) << 9) + laneo;
            f.ah[i] = *(const bf16x8*)(Ahi + off);
            f.al[i] = *(const bf16x8*)(Alo + off);
        }
#pragma unroll
        for (int j = 0; j < NF; j++) {
            size_t off = ((size_t)((nt0 + j) * NKS + ks) << 9) + laneo;
            f.bh[j] = *(const bf16x8*)(Bhi + off);
            f.bl[j] = *(const bf16x8*)(Blo + off);
        }
    };

    f32x4 acc[2][NF];
#pragma unroll
    for (int i = 0; i < 2; i++)
#pragma unroll
        for (int j = 0; j < NF; j++) acc[i][j] = (f32x4){0.f, 0.f, 0.f, 0.f};

    Frag cur, nxt;
    loadF(0, cur);
#pragma unroll
    for (int ks = 0; ks < NKS; ++ks) {
        if (ks + 1 < NKS) loadF(ks + 1, nxt);   // issue next-stage loads first
#pragma unroll
        for (int i = 0; i < 2; i++)
#pragma unroll
            for (int j = 0; j < NF; j++) {
                acc[i][j] = __builtin_amdgcn_mfma_f32_16x16x32_bf16(cur.ah[i], cur.bh[j], acc[i][j], 0, 0, 0);
                acc[i][j] = __builtin_amdgcn_mfma_f32_16x16x32_bf16(cur.ah[i], cur.bl[j], acc[i][j], 0, 0, 0);
                acc[i][j] = __builtin_amdgcn_mfma_f32_16x16x32_bf16(cur.al[i], cur.bh[j], acc[i][j], 0, 0, 0);
            }
        if (ks + 1 < NKS) cur = nxt;
    }

    int crow = (lane >> 4) * 4;
    int ccol = lane & 15;
    float s_loc[NF], q_loc[NF];
#pragma unroll
    for (int j = 0; j < NF; j++) { s_loc[j] = 0.f; q_loc[j] = 0.f; }
#pragma unroll
    for (int i = 0; i < 2; i++) {
        int rowb = (mt0 + i) * 16 + crow;
#pragma unroll
        for (int j = 0; j < NF; j++) {
            int col = (nt0 + j) * 16 + ccol;
            float bv = (col < realN) ? bias[col] : 0.f;
#pragma unroll
            for (int r = 0; r < 4; r++) {
                int row = rowb + r;
                float v = acc[i][j][r] + bv;
                if (EPI == 0) {
                    v = fmaxf(v, 0.f);
                    unsigned short hi, lo;
                    splitbf(v, hi, lo);
                    size_t a = packAddr(row, col, nks_out);
                    Phi[a] = hi; Plo[a] = lo;
                } else {
                    if (row < realM) {
                        s_loc[j] += v;
                        q_loc[j] += v * v;
                        if (col < realN) {
                            Hb16[(size_t)row * PD + col] = bf16hi(v);
                            if (Cf32) Cf32[(size_t)row * realN + col] = v;
                        }
                    }
                }
            }
        }
    }
    if constexpr (EPI == 1) {
        __shared__ float sms[BNT][8];
        __shared__ float smq[BNT][8];
        int slot = wm * 4 + (lane >> 4);
#pragma unroll
        for (int j = 0; j < NF; j++) {
            int cl = (wn * NF + j) * 16 + ccol;
            sms[cl][slot] = s_loc[j];
            smq[cl][slot] = q_loc[j];
        }
        __syncthreads();
        if (tid < BNT) {
            float ss = 0.f, qq = 0.f;
#pragma unroll
            for (int k = 0; k < 8; k++) { ss += sms[tid][k]; qq += smq[tid][k]; }
            int col = bx * BNT + tid;
            if (col < realN) {
                atomicAdd(&sums[col], ss);
                atomicAdd(&sums[304 + col], qq);
            }
        }
    }
}

// final-layer BN apply (writes h_node to d_out, no relu)
__global__ void k_bnapply(const float* __restrict__ hin, const float* __restrict__ sums,
                          const float* __restrict__ g, const float* __restrict__ b,
                          float* __restrict__ hout, int l, int relu) {
    int idx = blockIdx.x * blockDim.x + threadIdx.x;
    if (idx >= NN * DD) return;
    int c = idx % DD;
    const float invn = 1.0f / NN;
    float mu = sums[c] * invn;
    float var = sums[304 + c] * invn - mu * mu;
    float inv = rsqrtf(var + 1e-5f);
    float v = (hin[idx] - mu) * inv * g[l * DD + c] + b[l * DD + c];
    if (relu) v = fmaxf(v, 0.f);
    hout[idx] = v;
}

// ---------------- parallel pooling: run-length partial sums + atomics ----------------
__global__ __launch_bounds__(320) void k_pool(const float* __restrict__ h,
                                              const int* __restrict__ batch,
                                              float* __restrict__ pooled) {
    int c = threadIdx.x;
    if (c >= DD) return;
    int r0 = blockIdx.x * PROWS;
    int r1 = min(r0 + PROWS, NN);
    if (r0 >= NN) return;
    int gc = batch[r0];
    float acc = 0.f;
    for (int r = r0; r < r1; ++r) {
        int g = batch[r];
        if (g != gc) {
            atomicAdd(&pooled[gc * DD + c], acc);
            acc = 0.f; gc = g;
        }
        acc += h[(size_t)r * DD + c];
    }
    atomicAdd(&pooled[gc * DD + c], acc);
}

// ---------------- head GEMM (split-K) ----------------
template<int KD, int NW, int ACT>
__global__ __launch_bounds__(256) void k_hgemm(
    const float* __restrict__ A, const float* __restrict__ W,
    const float* __restrict__ bias, float* __restrict__ outp,
    const int* __restrict__ gs, const int* __restrict__ ge) {
    __shared__ float smA[KD];
    __shared__ float smR[8][32];
    int g = blockIdx.y;
    int t = threadIdx.x;
    float mul = 1.f;
    if (gs) {
        int cnt = ge[g] - gs[g];
        mul = 1.f / (float)((cnt > 0) ? cnt : 1);
    }
    for (int k = t; k < KD; k += 256) smA[k] = A[(size_t)g * KD + k] * mul;
    __syncthreads();
    int c = blockIdx.x * 32 + (t & 31);
    int s = t >> 5;
    float acc = 0.f;
#pragma unroll 4
    for (int k = s; k < KD; k += 8)
        acc = fmaf(smA[k], W[(size_t)k * NW + c], acc);
    smR[s][t & 31] = acc;
    __syncthreads();
    if (t < 32) {
        float r = bias[c];
#pragma unroll
        for (int i = 0; i < 8; i++) r += smR[i][t];
        if (ACT) r = fmaxf(r, 0.f) + log1pf(expf(-fabsf(r)));
        outp[(size_t)g * NW + c] = r;
    }
}

__global__ __launch_bounds__(256) void k_hfinal(const float* __restrict__ z,
                                                const float* __restrict__ w,
                                                const float* __restrict__ b,
                                                float* __restrict__ pred) {
    __shared__ float smR[4];
    int g = blockIdx.x, t = threadIdx.x;
    float rv = z[(size_t)g * HDIM + t] * w[t];
#pragma unroll
    for (int off = 32; off > 0; off >>= 1) rv += __shfl_down(rv, off, 64);
    if ((t & 63) == 0) smR[t >> 6] = rv;
    __syncthreads();
    if (t == 0) pred[g] = smR[0] + smR[1] + smR[2] + smR[3] + b[0];
}

extern "C" void kernel_launch(void* const* d_in, const int* in_sizes, int n_in,
                              void* d_out, int out_size, void* d_ws, size_t ws_size,
                              hipStream_t stream) {
    const int* x          = (const int*)d_in[0];
    const int* edge_index = (const int*)d_in[1];
    const int* edge_attr  = (const int*)d_in[2];
    const int* batch      = (const int*)d_in[3];
    const float* x_emb1   = (const float*)d_in[4];
    const float* x_emb2   = (const float*)d_in[5];
    const float* mlp_w1   = (const float*)d_in[6];
    const float* mlp_b1   = (const float*)d_in[7];
    const float* mlp_w2   = (const float*)d_in[8];
    const float* mlp_b2   = (const float*)d_in[9];
    const float* ee1      = (const float*)d_in[10];
    const float* ee2      = (const float*)d_in[11];
    const float* ee3w     = (const float*)d_in[12];
    const float* ee3b     = (const float*)d_in[13];
    const float* bng      = (const float*)d_in[14];
    const float* bnb      = (const float*)d_in[15];
    const float* feat_w   = (const float*)d_in[16];
    const float* feat_b   = (const float*)d_in[17];
    const float* ph_w1    = (const float*)d_in[18];
    const float* ph_b1    = (const float*)d_in[19];
    const float* ph_w2    = (const float*)d_in[20];
    const float* ph_b2    = (const float*)d_in[21];
    const float* ph_w3    = (const float*)d_in[22];
    const float* ph_b3    = (const float*)d_in[23];
    float* out = (float*)d_out;

    // workspace layout (f32 elements)
    float* fws = (float*)d_ws;
    size_t o = 0;
    float* hbuf  = fws + o; o += (size_t)NN * DD;                    // f32 h_pre (final layer only)
    unsigned short* hb16 = (unsigned short*)(fws + o); o += (size_t)NN * PD / 2 + 8;  // bf16 h plane (PD stride)
    float* hf    = fws + o; o += (size_t)GG * FDIM;
    float* z1    = fws + o; o += (size_t)GG * HDIM;
    float* z2    = fws + o; o += (size_t)GG * HDIM;
    unsigned short* A1lo = (unsigned short*)(fws + o); o += (size_t)(MP/16) * NKS1 * 512 / 2;
    unsigned short* A2hi = (unsigned short*)(fws + o); o += (size_t)(MP/16) * NKS2 * 512 / 2;
    unsigned short* A2lo = (unsigned short*)(fws + o); o += (size_t)(MP/16) * NKS2 * 512 / 2;
    unsigned short* B1hi = (unsigned short*)(fws + o); o += (size_t)LL * B1PLANE / 2;
    unsigned short* B1lo = (unsigned short*)(fws + o); o += (size_t)LL * B1PLANE / 2;
    unsigned short* B2hi = (unsigned short*)(fws + o); o += (size_t)LL * B2PLANE / 2;
    unsigned short* B2lo = (unsigned short*)(fws + o); o += (size_t)LL * B2PLANE / 2;
    unsigned* rowptr = (unsigned*)(fws + o); o += NN + 8;
    unsigned* eidx   = (unsigned*)(fws + o); o += EE + NN;
    // ---- zeroed region (single memset) ----
    float* zbase = fws + o;
    unsigned* deg    = (unsigned*)(fws + o); o += NN;
    unsigned* cursor = (unsigned*)(fws + o); o += NN;
    float* sumsL  = fws + o; o += 5 * 640;       // per-layer BN stats
    float* pooled = fws + o; o += (size_t)GG * DD;
    int* gs = (int*)(fws + o); o += GG;
    int* ge = (int*)(fws + o); o += GG;
    size_t zbytes = (size_t)((char*)(fws + o) - (char*)zbase);
    (void)ws_size; (void)in_sizes; (void)n_in; (void)out_size;

    // A1hi aliases d_out (scratch until final bnapply overwrites it)
    unsigned short* A1hi = (unsigned short*)out;

    const int TPB = 256;
    int gridE = (EE + NN + TPB - 1) / TPB;
    int gridND = (NN * DD + TPB - 1) / TPB;

    hipMemsetAsync(zbase, 0, zbytes, stream);
    k_node_emb<<<gridND, TPB, 0, stream>>>(x, x_emb1, x_emb2, hb16);
    k_count<<<gridE, TPB, 0, stream>>>(edge_index, deg);
    k_scan<<<1, 256, 0, stream>>>(deg, rowptr);
    k_fill<<<gridE, TPB, 0, stream>>>(edge_index, edge_attr, rowptr, cursor, eidx);
    k_bounds2<<<(NN + TPB - 1) / TPB, TPB, 0, stream>>>(batch, gs, ge);
    k_packAll<<<(LL * (KP1 * NP1 + KP2 * NP2) + TPB - 1) / TPB, TPB, 0, stream>>>(
        mlp_w1, mlp_w2, B1hi, B1lo, B2hi, B2lo);

    for (int l = 0; l < LL; ++l) {
        if (l == 0)
            k_gather<0><<<NN / 4, TPB, 0, stream>>>(hb16, rowptr, eidx,
                nullptr, nullptr, nullptr, 0, ee1, ee2, ee3w, ee3b, l, A1hi, A1lo);
        else
            k_gather<1><<<NN / 4, TPB, 0, stream>>>(hb16, rowptr, eidx,
                sumsL + (size_t)(l - 1) * 640, bng, bnb, l - 1,
                ee1, ee2, ee3w, ee3b, l, A1hi, A1lo);
        // GEMM1: [MP,320] x [320,640] -> relu -> packed A2   (NF=4 -> BNT=128)
        k_mgemm<4, NKS1, 0><<<NWG, 256, 0, stream>>>(
            A1hi, A1lo, B1hi + (size_t)l * B1PLANE, B1lo + (size_t)l * B1PLANE,
            mlp_b1 + (size_t)l * 2 * DD, 2 * DD,
            nullptr, 0, A2hi, A2lo, NKS2, nullptr, nullptr);
        // GEMM2: [MP,640] x [640,320] -> bf16 h plane (+ f32 final layer) + BN stats (NF=2 -> BNT=64)
        k_mgemm<2, NKS2, 1><<<NWG, 256, 0, stream>>>(
            A2hi, A2lo, B2hi + (size_t)l * B2PLANE, B2lo + (size_t)l * B2PLANE,
            mlp_b2 + (size_t)l * DD, DD,
            (l == LL - 1) ? hbuf : nullptr, NN, nullptr, nullptr, 0,
            sumsL + (size_t)l * 640, hb16);
    }
    // final layer BN -> h_node output (no relu)
    k_bnapply<<<gridND, TPB, 0, stream>>>(hbuf, sumsL + 4 * 640, bng, bnb, out, LL - 1, 0);

    k_pool<<<(NN + PROWS - 1) / PROWS, 320, 0, stream>>>(out, batch, pooled);
    k_hgemm<DD, FDIM, 0><<<dim3(FDIM / 32, GG), 256, 0, stream>>>(pooled, feat_w, feat_b, hf, gs, ge);
    k_hgemm<FDIM, HDIM, 1><<<dim3(HDIM / 32, GG), 256, 0, stream>>>(hf, ph_w1, ph_b1, z1, nullptr, nullptr);
    k_hgemm<HDIM, HDIM, 1><<<dim3(HDIM / 32, GG), 256, 0, stream>>>(z1, ph_w2, ph_b2, z2, nullptr, nullptr);
    k_hfinal<<<GG, 256, 0, stream>>>(z2, ph_w3, ph_b3, out + (size_t)NN * DD);
}

// Round 17
// 540.374 us; speedup vs baseline: 1.1012x; 1.0192x over previous
//
#include <hip/hip_runtime.h>
#include <hip/hip_bf16.h>
#include <math.h>

#define NN 10000
#define EE 160000
#define DD 300
#define LL 5
#define GG 64
#define FDIM 512
#define HDIM 256

// padded GEMM dims
#define MP 10112          // 158 * 64
#define KP1 320           // K of GEMM1 (=DD padded), NKS1 = 10
#define NP1 640           // N of GEMM1 (=2D padded)
#define KP2 640           // K of GEMM2, NKS2 = 20
#define NP2 320           // N of GEMM2
#define NKS1 10
#define NKS2 20
#define PROWS 25          // rows per k_pool block
#define PD 384            // hb16 row stride (u16): 768B = 3*256B -> aligned wave loads
#define B1PLANE 204800    // (NP1/16)*NKS1*512 u16 per layer
#define B2PLANE 204800    // (NP2/16)*NKS2*512 u16 per layer
#define NWG 790           // 5 x-panels * 158 y-panels of 64 rows (both GEMMs)

typedef short bf16x8 __attribute__((ext_vector_type(8)));
typedef float f32x4 __attribute__((ext_vector_type(4)));

// round-to-nearest-even f32 -> bf16 (hi) and hi+lo split
__device__ inline unsigned short bf16hi(float v) {
    unsigned u = __builtin_bit_cast(unsigned, v);
    unsigned r = u + 0x7FFFu + ((u >> 16) & 1u);
    return (unsigned short)(r >> 16);
}
__device__ inline void splitbf(float v, unsigned short& hi, unsigned short& lo) {
    hi = bf16hi(v);
    float hf = __builtin_bit_cast(float, (unsigned)hi << 16);
    lo = bf16hi(v - hf);
}

// fragment-packed element address. For A: row=m, k=k. For B: row=n, k=k.
// frag: lane = (row&15) + 16*((k>>3)&3), elem = k&7, tile = (row>>4)*nks + (k>>5)
__device__ inline size_t packAddr(int row, int k, int nks) {
    return ((size_t)((row >> 4) * nks + (k >> 5)) << 9)
         + (size_t)((((row & 15) + (((k >> 3) & 3) << 4)) << 3) + (k & 7));
}

// ---------------- node embedding -> bf16 plane (PD-padded rows) ----------------
__global__ void k_node_emb(const int* __restrict__ x, const float* __restrict__ e1,
                           const float* __restrict__ e2, unsigned short* __restrict__ hb) {
    int idx = blockIdx.x * blockDim.x + threadIdx.x;
    if (idx >= NN * DD) return;
    int r = idx / DD, c = idx - r * DD;
    int i0 = x[r * 2 + 0], i1 = x[r * 2 + 1];
    hb[(size_t)r * PD + c] = bf16hi(e1[i0 * DD + c] + e2[i1 * DD + c]);
}

// ---------------- CSR build over dst ----------------
__global__ void k_count(const int* __restrict__ edge_index, unsigned* __restrict__ deg) {
    int e = blockIdx.x * blockDim.x + threadIdx.x;
    if (e >= EE + NN) return;
    int dst = (e < EE) ? edge_index[EE + e] : (e - EE);
    atomicAdd(&deg[dst], 1u);
}

__global__ void k_scan(const unsigned* __restrict__ deg, unsigned* __restrict__ row_ptr) {
    __shared__ unsigned sm[256];
    int t = threadIdx.x;
    unsigned loc[40];
    unsigned run = 0;
    int base = t * 40;
#pragma unroll
    for (int i = 0; i < 40; i++) {
        int idx = base + i;
        unsigned d = (idx < NN) ? deg[idx] : 0u;
        loc[i] = run; run += d;
    }
    sm[t] = run;
    __syncthreads();
    for (int off = 1; off < 256; off <<= 1) {
        unsigned v = (t >= off) ? sm[t - off] : 0u;
        __syncthreads();
        sm[t] += v;
        __syncthreads();
    }
    unsigned pre = (t > 0) ? sm[t - 1] : 0u;
#pragma unroll
    for (int i = 0; i < 40; i++) {
        int idx = base + i;
        if (idx < NN) row_ptr[idx] = pre + loc[i];
    }
    if (t == 255) row_ptr[NN] = sm[255];
}

__global__ void k_fill(const int* __restrict__ edge_index, const int* __restrict__ edge_attr,
                       const unsigned* __restrict__ row_ptr, unsigned* __restrict__ cursor,
                       unsigned* __restrict__ eidx) {
    int e = blockIdx.x * blockDim.x + threadIdx.x;
    if (e >= EE + NN) return;
    int src, dst, code;
    if (e < EE) {
        src = edge_index[e];
        dst = edge_index[EE + e];
        const int* ea = edge_attr + e * 10;
        int a0 = ea[0] & 1, a1 = ea[1] & 1, bits = 0;
#pragma unroll
        for (int k = 0; k < 8; k++) bits |= (ea[2 + k] & 1) << k;
        code = a0 | (a1 << 1) | (bits << 2);
    } else {
        src = e - EE; dst = e - EE; code = 1024;
    }
    unsigned pos = atomicAdd(&cursor[dst], 1u);
    eidx[row_ptr[dst] + pos] = (unsigned)src | ((unsigned)code << 16);
}

// ---------------- graph bounds (batch sorted -> unique writers, no atomics) ----------------
__global__ void k_bounds2(const int* __restrict__ batch, int* __restrict__ gs,
                          int* __restrict__ ge) {
    int i = blockIdx.x * blockDim.x + threadIdx.x;
    if (i >= NN) return;
    int g = batch[i];
    if (i == 0 || batch[i - 1] != g) gs[g] = i;
    if (i == NN - 1 || batch[i + 1] != g) ge[g] = i + 1;
}

// ---------------- aggregation: one wave/node, bf16 h reads (PD stride), unroll-8 ILP ----------------
// channels per lane: c = (q>>1)*128 + 2*lane + (q&1), q=0..5 (q>=4 only lanes<22)
template<int MODE>
__global__ __launch_bounds__(256) void k_gather(
    const unsigned short* __restrict__ hb,
    const unsigned* __restrict__ row_ptr, const unsigned* __restrict__ eidx,
    const float* __restrict__ sums,
    const float* __restrict__ bng, const float* __restrict__ bnb, int lprev,
    const float* __restrict__ ee1, const float* __restrict__ ee2,
    const float* __restrict__ ee3w, const float* __restrict__ ee3b, int l,
    unsigned short* __restrict__ A1hi, unsigned short* __restrict__ A1lo) {
    int wave = threadIdx.x >> 6, lane = threadIdx.x & 63;
    int v = blockIdx.x * 4 + wave;
    if (v >= NN) return;
    const int c2l = 2 * lane;
    const bool has2 = (lane < (DD - 256) / 2);   // lanes 0..21
    float sc[6], sh[6];
    if (MODE == 1) {
#pragma unroll
        for (int q = 0; q < 6; q++) {
            int c = (q >> 1) * 128 + c2l + (q & 1);
            if (q < 4 || has2) {
                float mu = sums[c] * (1.0f / NN);
                float var = sums[304 + c] * (1.0f / NN) - mu * mu;
                float inv = rsqrtf(var + 1e-5f);
                sc[q] = bng[lprev * DD + c] * inv;
                sh[q] = bnb[lprev * DD + c] - mu * sc[q];
            } else { sc[q] = 0.f; sh[q] = 0.f; }
        }
    }
    float a[6] = {0.f, 0.f, 0.f, 0.f, 0.f, 0.f};
    unsigned s = row_ptr[v], e = row_ptr[v + 1];
    unsigned n01 = 0, sb0 = 0, sb1 = 0;
    auto edge = [&](unsigned p) {
        int src = (int)(p & 0xFFFFu);
        unsigned code = p >> 16;
        n01 += (code * 0x8001u) & 0x10001u;
        sb0 += (((code >> 2) & 0xFu) * 0x204081u) & 0x1010101u;
        sb1 += (((code >> 6) & 0xFu) * 0x204081u) & 0x1010101u;
        const unsigned short* hr = hb + (size_t)src * PD;
        unsigned w0 = *(const unsigned*)(hr + c2l);
        unsigned w1 = *(const unsigned*)(hr + 128 + c2l);
        unsigned w2 = has2 ? *(const unsigned*)(hr + 256 + c2l) : 0u;
        float x0 = __builtin_bit_cast(float, w0 << 16);
        float x1 = __builtin_bit_cast(float, w0 & 0xFFFF0000u);
        float x2 = __builtin_bit_cast(float, w1 << 16);
        float x3 = __builtin_bit_cast(float, w1 & 0xFFFF0000u);
        float x4 = __builtin_bit_cast(float, w2 << 16);
        float x5 = __builtin_bit_cast(float, w2 & 0xFFFF0000u);
        if (MODE == 1) {
            x0 = fmaxf(fmaf(x0, sc[0], sh[0]), 0.f);
            x1 = fmaxf(fmaf(x1, sc[1], sh[1]), 0.f);
            x2 = fmaxf(fmaf(x2, sc[2], sh[2]), 0.f);
            x3 = fmaxf(fmaf(x3, sc[3], sh[3]), 0.f);
            x4 = fmaxf(fmaf(x4, sc[4], sh[4]), 0.f);
            x5 = fmaxf(fmaf(x5, sc[5], sh[5]), 0.f);
        }
        a[0] += x0; a[1] += x1; a[2] += x2; a[3] += x3; a[4] += x4; a[5] += x5;
    };
    // unroll-8: 8 sequential eidx reads (merge to 2x dwordx4) -> up to 24 h-row
    // dword loads in flight per wave (per-wave MLP is the binding constraint;
    // unroll 2->4 measured 65->45 us, so push toward the outstanding-miss limit).
    unsigned i = s;
    for (; i + 7 < e; i += 8) {
        unsigned p0 = eidx[i],     p1 = eidx[i + 1], p2 = eidx[i + 2], p3 = eidx[i + 3];
        unsigned p4 = eidx[i + 4], p5 = eidx[i + 5], p6 = eidx[i + 6], p7 = eidx[i + 7];
        edge(p0); edge(p1); edge(p2); edge(p3);
        edge(p4); edge(p5); edge(p6); edge(p7);
    }
    for (; i + 3 < e; i += 4) {
        unsigned p0 = eidx[i], p1 = eidx[i + 1], p2 = eidx[i + 2], p3 = eidx[i + 3];
        edge(p0); edge(p1); edge(p2); edge(p3);
    }
    for (; i < e; ++i) edge(eidx[i]);

    float deg = (float)(e - s);
    float na0 = (float)(n01 & 0xFFFFu);
    float na1 = (float)(n01 >> 16);
    float sb[8] = {(float)(sb0 & 255u), (float)((sb0 >> 8) & 255u),
                   (float)((sb0 >> 16) & 255u), (float)(sb0 >> 24),
                   (float)(sb1 & 255u), (float)((sb1 >> 8) & 255u),
                   (float)((sb1 >> 16) & 255u), (float)(sb1 >> 24)};
    const float* E10 = ee1 + (size_t)(l * 6 + 0) * DD;
    const float* E11 = ee1 + (size_t)(l * 6 + 1) * DD;
    const float* E14 = ee1 + (size_t)(l * 6 + 4) * DD;
    const float* E20 = ee2 + (size_t)(l * 4 + 0) * DD;
    const float* E21 = ee2 + (size_t)(l * 4 + 1) * DD;
    const float* B3  = ee3b + (size_t)l * DD;
    unsigned short hi, lo;
    size_t ad;
#pragma unroll
    for (int q = 0; q < 6; q++) {
        if (q < 4 || has2) {
            int c = (q >> 1) * 128 + c2l + (q & 1);
            float t = a[q];
            t += (deg - 1.f - na0) * E10[c] + na0 * E11[c] + E14[c];
            t += (deg - na1) * E20[c] + na1 * E21[c];
            t += deg * B3[c];
#pragma unroll
            for (int k = 0; k < 8; k++)
                t += sb[k] * (ee3w + (size_t)(l * 8 + k) * DD)[c];
            splitbf(t, hi, lo);
            ad = packAddr(v, c, NKS1);
            A1hi[ad] = hi; A1lo[ad] = lo;
        }
    }
    // CRITICAL: zero the k-padding columns [300,320). A1hi aliases d_out, so on
    // graph replays this region holds recycled h_node bytes which can decode to
    // bf16 NaN/Inf; NaN * 0 (zero-padded B) = NaN poisons entire C rows.
    if (lane < KP1 - DD) {
        ad = packAddr(v, DD + lane, NKS1);
        A1hi[ad] = 0; A1lo[ad] = 0;
    }
}

// ---------------- weight pack for ALL layers (zero-fills padding) ----------------
__global__ void k_packAll(const float* __restrict__ mlp_w1, const float* __restrict__ mlp_w2,
                          unsigned short* __restrict__ B1hi, unsigned short* __restrict__ B1lo,
                          unsigned short* __restrict__ B2hi, unsigned short* __restrict__ B2lo) {
    const int PER = KP1 * NP1 + KP2 * NP2;
    int idx = blockIdx.x * blockDim.x + threadIdx.x;
    int l = idx / PER;
    if (l >= LL) return;
    int r = idx - l * PER;
    unsigned short hi, lo;
    if (r < KP1 * NP1) {
        int nn = r / KP1, kk = r - nn * KP1;
        float v = (kk < DD && nn < 2 * DD)
                ? mlp_w1[(size_t)l * DD * 2 * DD + (size_t)kk * (2 * DD) + nn] : 0.f;
        splitbf(v, hi, lo);
        size_t a = (size_t)l * B1PLANE + packAddr(nn, kk, NKS1);
        B1hi[a] = hi; B1lo[a] = lo;
    } else {
        r -= KP1 * NP1;
        int nn = r / KP2, kk = r - nn * KP2;
        float v = (kk < 2 * DD && nn < DD)
                ? mlp_w2[(size_t)l * 2 * DD * DD + (size_t)kk * DD + nn] : 0.f;
        splitbf(v, hi, lo);
        size_t a = (size_t)l * B2PLANE + packAddr(nn, kk, NKS2);
        B2hi[a] = hi; B2lo[a] = lo;
    }
}

// ---------------- MFMA GEMM: 64-row blocks, XCD swizzle, 2-deep register pipeline ----------------
// 4 waves: wm=wave>>1 (2 m-tiles each), wn=wave&1 (NF n-frags each). BNT = 32*NF.
// K-loop fully unrolled; fragments for ks+1 are loaded into a second register set
// BEFORE the MFMAs of ks (loads independent of MFMAs -> L2 latency hides under MFMA).
// EPI 0: relu(acc+bias) -> packed bf16 hi/lo (next GEMM's A)
// EPI 1: acc+bias -> bf16 h plane (PD stride) (+ optional f32 C) + fused BN stats
template<int NF, int NKS, int EPI>
__global__ __launch_bounds__(256) void k_mgemm(
    const unsigned short* __restrict__ Ahi, const unsigned short* __restrict__ Alo,
    const unsigned short* __restrict__ Bhi, const unsigned short* __restrict__ Blo,
    const float* __restrict__ bias, int realN,
    float* __restrict__ Cf32, int realM,
    unsigned short* __restrict__ Phi, unsigned short* __restrict__ Plo, int nks_out,
    float* __restrict__ sums, unsigned short* __restrict__ Hb16) {
    constexpr int BNT = 32 * NF;
    // bijective XCD swizzle (m204): NWG=790, q=98, r=6; same-XCD blocks get
    // consecutive wgid -> complete 5-x-panel groups -> A-panel L2 reuse per XCD.
    int orig = blockIdx.x;
    int xcd = orig & 7, rem = orig >> 3;
    int wgid = (xcd < 6 ? xcd * 99 : 594 + (xcd - 6) * 98) + rem;
    int by = wgid / 5;          // 158 m-panels of 64 rows
    int bx = wgid - by * 5;     // 5 n-panels of BNT cols
    int tid = threadIdx.x;
    int lane = tid & 63, wave = tid >> 6;
    int wm = wave >> 1, wn = wave & 1;
    int mt0 = by * 4 + wm * 2;
    int nt0 = bx * (2 * NF) + wn * NF;
    const int laneo = lane * 8;

    struct Frag { bf16x8 ah[2], al[2], bh[NF], bl[NF]; };
    auto loadF = [&](int ks, Frag& f) {
#pragma unroll
        for (int i = 0; i < 2; i++) {
            size_t off = ((size_t)((mt0 + i) * NKS + ks) << 9) + laneo;
            f.ah[i] = *(const bf16x8*)(Ahi + off);
            f.al[i] = *(const bf16x8*)(Alo + off);
        }
#pragma unroll
        for (int j = 0; j < NF; j++) {
            size_t off = ((size_t)((nt0 + j) * NKS + ks) << 9) + laneo;
            f.bh[j] = *(const bf16x8*)(Bhi + off);
            f.bl[j] = *(const bf16x8*)(Blo + off);
        }
    };

    f32x4 acc[2][NF];
#pragma unroll
    for (int i = 0; i < 2; i++)
#pragma unroll
        for (int j = 0; j < NF; j++) acc[i][j] = (f32x4){0.f, 0.f, 0.f, 0.f};

    Frag cur, nxt;
    loadF(0, cur);
#pragma unroll
    for (int ks = 0; ks < NKS; ++ks) {
        if (ks + 1 < NKS) loadF(ks + 1, nxt);   // issue next-stage loads first
#pragma unroll
        for (int i = 0; i < 2; i++)
#pragma unroll
            for (int j = 0; j < NF; j++) {
                acc[i][j] = __builtin_amdgcn_mfma_f32_16x16x32_bf16(cur.ah[i], cur.bh[j], acc[i][j], 0, 0, 0);
                acc[i][j] = __builtin_amdgcn_mfma_f32_16x16x32_bf16(cur.ah[i], cur.bl[j], acc[i][j], 0, 0, 0);
                acc[i][j] = __builtin_amdgcn_mfma_f32_16x16x32_bf16(cur.al[i], cur.bh[j], acc[i][j], 0, 0, 0);
            }
        if (ks + 1 < NKS) cur = nxt;
    }

    int crow = (lane >> 4) * 4;
    int ccol = lane & 15;
    float s_loc[NF], q_loc[NF];
#pragma unroll
    for (int j = 0; j < NF; j++) { s_loc[j] = 0.f; q_loc[j] = 0.f; }
#pragma unroll
    for (int i = 0; i < 2; i++) {
        int rowb = (mt0 + i) * 16 + crow;
#pragma unroll
        for (int j = 0; j < NF; j++) {
            int col = (nt0 + j) * 16 + ccol;
            float bv = (col < realN) ? bias[col] : 0.f;
#pragma unroll
            for (int r = 0; r < 4; r++) {
                int row = rowb + r;
                float v = acc[i][j][r] + bv;
                if (EPI == 0) {
                    v = fmaxf(v, 0.f);
                    unsigned short hi, lo;
                    splitbf(v, hi, lo);
                    size_t a = packAddr(row, col, nks_out);
                    Phi[a] = hi; Plo[a] = lo;
                } else {
                    if (row < realM) {
                        s_loc[j] += v;
                        q_loc[j] += v * v;
                        if (col < realN) {
                            Hb16[(size_t)row * PD + col] = bf16hi(v);
                            if (Cf32) Cf32[(size_t)row * realN + col] = v;
                        }
                    }
                }
            }
        }
    }
    if constexpr (EPI == 1) {
        __shared__ float sms[BNT][8];
        __shared__ float smq[BNT][8];
        int slot = wm * 4 + (lane >> 4);
#pragma unroll
        for (int j = 0; j < NF; j++) {
            int cl = (wn * NF + j) * 16 + ccol;
            sms[cl][slot] = s_loc[j];
            smq[cl][slot] = q_loc[j];
        }
        __syncthreads();
        if (tid < BNT) {
            float ss = 0.f, qq = 0.f;
#pragma unroll
            for (int k = 0; k < 8; k++) { ss += sms[tid][k]; qq += smq[tid][k]; }
            int col = bx * BNT + tid;
            if (col < realN) {
                atomicAdd(&sums[col], ss);
                atomicAdd(&sums[304 + col], qq);
            }
        }
    }
}

// final-layer BN apply (writes h_node to d_out, no relu)
__global__ void k_bnapply(const float* __restrict__ hin, const float* __restrict__ sums,
                          const float* __restrict__ g, const float* __restrict__ b,
                          float* __restrict__ hout, int l, int relu) {
    int idx = blockIdx.x * blockDim.x + threadIdx.x;
    if (idx >= NN * DD) return;
    int c = idx % DD;
    const float invn = 1.0f / NN;
    float mu = sums[c] * invn;
    float var = sums[304 + c] * invn - mu * mu;
    float inv = rsqrtf(var + 1e-5f);
    float v = (hin[idx] - mu) * inv * g[l * DD + c] + b[l * DD + c];
    if (relu) v = fmaxf(v, 0.f);
    hout[idx] = v;
}

// ---------------- parallel pooling: run-length partial sums + atomics ----------------
__global__ __launch_bounds__(320) void k_pool(const float* __restrict__ h,
                                              const int* __restrict__ batch,
                                              float* __restrict__ pooled) {
    int c = threadIdx.x;
    if (c >= DD) return;
    int r0 = blockIdx.x * PROWS;
    int r1 = min(r0 + PROWS, NN);
    if (r0 >= NN) return;
    int gc = batch[r0];
    float acc = 0.f;
    for (int r = r0; r < r1; ++r) {
        int g = batch[r];
        if (g != gc) {
            atomicAdd(&pooled[gc * DD + c], acc);
            acc = 0.f; gc = g;
        }
        acc += h[(size_t)r * DD + c];
    }
    atomicAdd(&pooled[gc * DD + c], acc);
}

// ---------------- head GEMM (split-K) ----------------
template<int KD, int NW, int ACT>
__global__ __launch_bounds__(256) void k_hgemm(
    const float* __restrict__ A, const float* __restrict__ W,
    const float* __restrict__ bias, float* __restrict__ outp,
    const int* __restrict__ gs, const int* __restrict__ ge) {
    __shared__ float smA[KD];
    __shared__ float smR[8][32];
    int g = blockIdx.y;
    int t = threadIdx.x;
    float mul = 1.f;
    if (gs) {
        int cnt = ge[g] - gs[g];
        mul = 1.f / (float)((cnt > 0) ? cnt : 1);
    }
    for (int k = t; k < KD; k += 256) smA[k] = A[(size_t)g * KD + k] * mul;
    __syncthreads();
    int c = blockIdx.x * 32 + (t & 31);
    int s = t >> 5;
    float acc = 0.f;
#pragma unroll 4
    for (int k = s; k < KD; k += 8)
        acc = fmaf(smA[k], W[(size_t)k * NW + c], acc);
    smR[s][t & 31] = acc;
    __syncthreads();
    if (t < 32) {
        float r = bias[c];
#pragma unroll
        for (int i = 0; i < 8; i++) r += smR[i][t];
        if (ACT) r = fmaxf(r, 0.f) + log1pf(expf(-fabsf(r)));
        outp[(size_t)g * NW + c] = r;
    }
}

__global__ __launch_bounds__(256) void k_hfinal(const float* __restrict__ z,
                                                const float* __restrict__ w,
                                                const float* __restrict__ b,
                                                float* __restrict__ pred) {
    __shared__ float smR[4];
    int g = blockIdx.x, t = threadIdx.x;
    float rv = z[(size_t)g * HDIM + t] * w[t];
#pragma unroll
    for (int off = 32; off > 0; off >>= 1) rv += __shfl_down(rv, off, 64);
    if ((t & 63) == 0) smR[t >> 6] = rv;
    __syncthreads();
    if (t == 0) pred[g] = smR[0] + smR[1] + smR[2] + smR[3] + b[0];
}

extern "C" void kernel_launch(void* const* d_in, const int* in_sizes, int n_in,
                              void* d_out, int out_size, void* d_ws, size_t ws_size,
                              hipStream_t stream) {
    const int* x          = (const int*)d_in[0];
    const int* edge_index = (const int*)d_in[1];
    const int* edge_attr  = (const int*)d_in[2];
    const int* batch      = (const int*)d_in[3];
    const float* x_emb1   = (const float*)d_in[4];
    const float* x_emb2   = (const float*)d_in[5];
    const float* mlp_w1   = (const float*)d_in[6];
    const float* mlp_b1   = (const float*)d_in[7];
    const float* mlp_w2   = (const float*)d_in[8];
    const float* mlp_b2   = (const float*)d_in[9];
    const float* ee1      = (const float*)d_in[10];
    const float* ee2      = (const float*)d_in[11];
    const float* ee3w     = (const float*)d_in[12];
    const float* ee3b     = (const float*)d_in[13];
    const float* bng      = (const float*)d_in[14];
    const float* bnb      = (const float*)d_in[15];
    const float* feat_w   = (const float*)d_in[16];
    const float* feat_b   = (const float*)d_in[17];
    const float* ph_w1    = (const float*)d_in[18];
    const float* ph_b1    = (const float*)d_in[19];
    const float* ph_w2    = (const float*)d_in[20];
    const float* ph_b2    = (const float*)d_in[21];
    const float* ph_w3    = (const float*)d_in[22];
    const float* ph_b3    = (const float*)d_in[23];
    float* out = (float*)d_out;

    // workspace layout (f32 elements)
    float* fws = (float*)d_ws;
    size_t o = 0;
    float* hbuf  = fws + o; o += (size_t)NN * DD;                    // f32 h_pre (final layer only)
    unsigned short* hb16 = (unsigned short*)(fws + o); o += (size_t)NN * PD / 2 + 8;  // bf16 h plane (PD stride)
    float* hf    = fws + o; o += (size_t)GG * FDIM;
    float* z1    = fws + o; o += (size_t)GG * HDIM;
    float* z2    = fws + o; o += (size_t)GG * HDIM;
    unsigned short* A1lo = (unsigned short*)(fws + o); o += (size_t)(MP/16) * NKS1 * 512 / 2;
    unsigned short* A2hi = (unsigned short*)(fws + o); o += (size_t)(MP/16) * NKS2 * 512 / 2;
    unsigned short* A2lo = (unsigned short*)(fws + o); o += (size_t)(MP/16) * NKS2 * 512 / 2;
    unsigned short* B1hi = (unsigned short*)(fws + o); o += (size_t)LL * B1PLANE / 2;
    unsigned short* B1lo = (unsigned short*)(fws + o); o += (size_t)LL * B1PLANE / 2;
    unsigned short* B2hi = (unsigned short*)(fws + o); o += (size_t)LL * B2PLANE / 2;
    unsigned short* B2lo = (unsigned short*)(fws + o); o += (size_t)LL * B2PLANE / 2;
    unsigned* rowptr = (unsigned*)(fws + o); o += NN + 8;
    unsigned* eidx   = (unsigned*)(fws + o); o += EE + NN;
    // ---- zeroed region (single memset) ----
    float* zbase = fws + o;
    unsigned* deg    = (unsigned*)(fws + o); o += NN;
    unsigned* cursor = (unsigned*)(fws + o); o += NN;
    float* sumsL  = fws + o; o += 5 * 640;       // per-layer BN stats
    float* pooled = fws + o; o += (size_t)GG * DD;
    int* gs = (int*)(fws + o); o += GG;
    int* ge = (int*)(fws + o); o += GG;
    size_t zbytes = (size_t)((char*)(fws + o) - (char*)zbase);
    (void)ws_size; (void)in_sizes; (void)n_in; (void)out_size;

    // A1hi aliases d_out (scratch until final bnapply overwrites it)
    unsigned short* A1hi = (unsigned short*)out;

    const int TPB = 256;
    int gridE = (EE + NN + TPB - 1) / TPB;
    int gridND = (NN * DD + TPB - 1) / TPB;

    hipMemsetAsync(zbase, 0, zbytes, stream);
    k_node_emb<<<gridND, TPB, 0, stream>>>(x, x_emb1, x_emb2, hb16);
    k_count<<<gridE, TPB, 0, stream>>>(edge_index, deg);
    k_scan<<<1, 256, 0, stream>>>(deg, rowptr);
    k_fill<<<gridE, TPB, 0, stream>>>(edge_index, edge_attr, rowptr, cursor, eidx);
    k_bounds2<<<(NN + TPB - 1) / TPB, TPB, 0, stream>>>(batch, gs, ge);
    k_packAll<<<(LL * (KP1 * NP1 + KP2 * NP2) + TPB - 1) / TPB, TPB, 0, stream>>>(
        mlp_w1, mlp_w2, B1hi, B1lo, B2hi, B2lo);

    for (int l = 0; l < LL; ++l) {
        if (l == 0)
            k_gather<0><<<NN / 4, TPB, 0, stream>>>(hb16, rowptr, eidx,
                nullptr, nullptr, nullptr, 0, ee1, ee2, ee3w, ee3b, l, A1hi, A1lo);
        else
            k_gather<1><<<NN / 4, TPB, 0, stream>>>(hb16, rowptr, eidx,
                sumsL + (size_t)(l - 1) * 640, bng, bnb, l - 1,
                ee1, ee2, ee3w, ee3b, l, A1hi, A1lo);
        // GEMM1: [MP,320] x [320,640] -> relu -> packed A2   (NF=4 -> BNT=128)
        k_mgemm<4, NKS1, 0><<<NWG, 256, 0, stream>>>(
            A1hi, A1lo, B1hi + (size_t)l * B1PLANE, B1lo + (size_t)l * B1PLANE,
            mlp_b1 + (size_t)l * 2 * DD, 2 * DD,
            nullptr, 0, A2hi, A2lo, NKS2, nullptr, nullptr);
        // GEMM2: [MP,640] x [640,320] -> bf16 h plane (+ f32 final layer) + BN stats (NF=2 -> BNT=64)
        k_mgemm<2, NKS2, 1><<<NWG, 256, 0, stream>>>(
            A2hi, A2lo, B2hi + (size_t)l * B2PLANE, B2lo + (size_t)l * B2PLANE,
            mlp_b2 + (size_t)l * DD, DD,
            (l == LL - 1) ? hbuf : nullptr, NN, nullptr, nullptr, 0,
            sumsL + (size_t)l * 640, hb16);
    }
    // final layer BN -> h_node output (no relu)
    k_bnapply<<<gridND, TPB, 0, stream>>>(hbuf, sumsL + 4 * 640, bng, bnb, out, LL - 1, 0);

    k_pool<<<(NN + PROWS - 1) / PROWS, 320, 0, stream>>>(out, batch, pooled);
    k_hgemm<DD, FDIM, 0><<<dim3(FDIM / 32, GG), 256, 0, stream>>>(pooled, feat_w, feat_b, hf, gs, ge);
    k_hgemm<FDIM, HDIM, 1><<<dim3(HDIM / 32, GG), 256, 0, stream>>>(hf, ph_w1, ph_b1, z1, nullptr, nullptr);
    k_hgemm<HDIM, HDIM, 1><<<dim3(HDIM / 32, GG), 256, 0, stream>>>(z1, ph_w2, ph_b2, z2, nullptr, nullptr);
    k_hfinal<<<GG, 256, 0, stream>>>(z2, ph_w3, ph_b3, out + (size_t)NN * DD);
}